// Round 1
// baseline (777.289 us; speedup 1.0000x reference)
//
#include <hip/hip_runtime.h>
#include <hip/hip_bf16.h>

// Problem constants
#define EMBED 1024
#define HEADS 16
#define HEAD_DIM 64
#define BATCH 2
#define SEQ 2048
#define MROWS (BATCH*SEQ)   // 4096
#define NQKV  (3*EMBED)     // 3072

typedef __attribute__((ext_vector_type(8))) short short8;
typedef __attribute__((ext_vector_type(4))) float float4v;

static __device__ __forceinline__ short f2bf(float f) {
    union { float f; unsigned u; } x; x.f = f;
    unsigned r = (x.u + 0x7FFFu + ((x.u >> 16) & 1u)) >> 16;
    return (short)r;
}

// ---------------- cast fp32 -> bf16 (8 elems/thread) ----------------
__global__ __launch_bounds__(256) void cast_bf16_k(const float* __restrict__ in,
                                                   short* __restrict__ out, int n8) {
    int i = blockIdx.x * 256 + threadIdx.x;
    if (i >= n8) return;
    const float4* p = (const float4*)in + (size_t)i * 2;
    float4 a = p[0], b = p[1];
    short8 o;
    o[0] = f2bf(a.x); o[1] = f2bf(a.y); o[2] = f2bf(a.z); o[3] = f2bf(a.w);
    o[4] = f2bf(b.x); o[5] = f2bf(b.y); o[6] = f2bf(b.z); o[7] = f2bf(b.w);
    *((short8*)out + i) = o;
}

// ---------------- transpose + cast: W[K][N] fp32 -> Wt[N][K] bf16 ----------------
__global__ __launch_bounds__(256) void transpose_cast_k(const float* __restrict__ W,
                                                        short* __restrict__ Wt,
                                                        int K, int N) {
    __shared__ float tile[32][33];
    int tx = threadIdx.x & 31, ty = threadIdx.x >> 5;  // ty 0..7
    int n0 = blockIdx.x * 32, k0 = blockIdx.y * 32;
#pragma unroll
    for (int i = 0; i < 4; i++)
        tile[ty + i * 8][tx] = W[(size_t)(k0 + ty + i * 8) * N + n0 + tx];
    __syncthreads();
#pragma unroll
    for (int i = 0; i < 4; i++)
        Wt[(size_t)(n0 + ty + i * 8) * K + k0 + tx] = f2bf(tile[tx][ty + i * 8]);
}

// ---------------- bf16 MFMA GEMM: C[M][N] = A[M][K] @ Bt[N][K]^T + bias ----------------
// 64x64 tile per block (256 threads, 4 waves; wave w = 16-row m-slice), K-chunk 32.
__global__ __launch_bounds__(256) void gemm_bf16_k(const short* __restrict__ A,
                                                   const short* __restrict__ Bt,
                                                   const float* __restrict__ bias,
                                                   float* __restrict__ outF,
                                                   short* __restrict__ outB,
                                                   int M, int N, int K) {
    __shared__ __align__(16) short As[64 * 40];
    __shared__ __align__(16) short Bs[64 * 40];
    const int tid = threadIdx.x;
    const int wave = tid >> 6, lane = tid & 63, quad = lane >> 4, l16 = lane & 15;
    const int m0 = blockIdx.x * 64, n0 = blockIdx.y * 64;

    float4v acc[4];
#pragma unroll
    for (int i = 0; i < 4; i++) acc[i] = (float4v){0.f, 0.f, 0.f, 0.f};

    const int r = tid >> 2, c8 = (tid & 3) * 8;
    for (int k0 = 0; k0 < K; k0 += 32) {
        __syncthreads();
        *(short8*)&As[r * 40 + c8] = *(const short8*)&A[(size_t)(m0 + r) * K + k0 + c8];
        *(short8*)&Bs[r * 40 + c8] = *(const short8*)&Bt[(size_t)(n0 + r) * K + k0 + c8];
        __syncthreads();
        short8 a = *(const short8*)&As[(wave * 16 + l16) * 40 + quad * 8];
#pragma unroll
        for (int ns = 0; ns < 4; ns++) {
            short8 b = *(const short8*)&Bs[(ns * 16 + l16) * 40 + quad * 8];
            acc[ns] = __builtin_amdgcn_mfma_f32_16x16x32_bf16(a, b, acc[ns], 0, 0, 0);
        }
    }
    // epilogue: C row = m0 + wave*16 + quad*4 + i ; col = n0 + ns*16 + l16
#pragma unroll
    for (int ns = 0; ns < 4; ns++) {
        int col = n0 + ns * 16 + l16;
        float bv = bias ? bias[col] : 0.f;
#pragma unroll
        for (int i = 0; i < 4; i++) {
            int row = m0 + wave * 16 + quad * 4 + i;
            float v = acc[ns][i] + bv;
            if (outF) outF[(size_t)row * N + col] = v;
            else      outB[(size_t)row * N + col] = f2bf(v);
        }
    }
}

// ---------------- fused causal attention ----------------
// Block = 256 thr (4 waves) handles one (b,h) and 32 query rows.
// Pass 1: online softmax stats via MFMA QK^T. Pass 2: recompute scores, write
// normalized weights fp32, P->LDS (bf16, A-layout), PV MFMA. Zero-fill upper tri.
__global__ __launch_bounds__(256) void attn_k(const short* __restrict__ qkv,
                                              float* __restrict__ wout,
                                              short* __restrict__ aheads) {
    __shared__ __align__(16) short Qs[32 * 72];
    __shared__ __align__(16) short Ks[32 * 72];
    __shared__ __align__(16) short Vt[64 * 40];
    __shared__ __align__(16) short Ps[32 * 40];
    __shared__ float Mred[2][32], Lred[2][32], Mfin[32], Lfin[32];

    const int tid = threadIdx.x;
    const int wave = tid >> 6, lane = tid & 63, quad = lane >> 4, l16 = lane & 15;
    const int qs = wave >> 1, ks = wave & 1;   // wave = (q-sub, k-sub / d-half)
    const int bh = blockIdx.x & 31;
    const int b = bh >> 4, h = bh & 15;
    const int qt = 63 - (blockIdx.x >> 5);     // heavy tiles first
    const int q0 = qt * 32;
    const int kend = q0 + 32;                  // exclusive causal k bound
    const int nch = kend >> 5;

    const short* qbase = qkv + (size_t)(b * SEQ) * NQKV + h * 64;
    const short* kbase = qbase + EMBED;
    const short* vbase = qbase + 2 * EMBED;
    float* wrow = wout + ((size_t)bh * SEQ + q0) * SEQ;

    // stage Q tile [32][64]
    {
        int r = tid >> 3, c8 = (tid & 7) * 8;
        *(short8*)&Qs[r * 72 + c8] = *(const short8*)&qbase[(size_t)(q0 + r) * NQKV + c8];
    }
    __syncthreads();
    const short8 aq0 = *(const short8*)&Qs[(qs * 16 + l16) * 72 + quad * 8];
    const short8 aq1 = *(const short8*)&Qs[(qs * 16 + l16) * 72 + 32 + quad * 8];

    const int kcol = ks * 16 + l16;  // lane's k column within a 32-chunk
    float mrun[4], lrun[4];
#pragma unroll
    for (int i = 0; i < 4; i++) { mrun[i] = -1e30f; lrun[i] = 0.f; }

    // ---- pass 1: stats ----
    for (int c = 0; c < nch; c++) {
        int kc = c * 32;
        __syncthreads();
        {
            int r = tid >> 3, c8 = (tid & 7) * 8;
            *(short8*)&Ks[r * 72 + c8] = *(const short8*)&kbase[(size_t)(kc + r) * NQKV + c8];
        }
        __syncthreads();
        short8 bk0 = *(const short8*)&Ks[(ks * 16 + l16) * 72 + quad * 8];
        short8 bk1 = *(const short8*)&Ks[(ks * 16 + l16) * 72 + 32 + quad * 8];
        float4v acc = (float4v){0.f, 0.f, 0.f, 0.f};
        acc = __builtin_amdgcn_mfma_f32_16x16x32_bf16(aq0, bk0, acc, 0, 0, 0);
        acc = __builtin_amdgcn_mfma_f32_16x16x32_bf16(aq1, bk1, acc, 0, 0, 0);
        int kg = kc + kcol;
#pragma unroll
        for (int i = 0; i < 4; i++) {
            int qg = q0 + qs * 16 + quad * 4 + i;
            if (kg <= qg) {
                float s = acc[i] * 0.125f;
                float mn = fmaxf(mrun[i], s);
                lrun[i] = lrun[i] * __expf(mrun[i] - mn) + __expf(s - mn);
                mrun[i] = mn;
            }
        }
    }
    // reduce across the 16 k-lanes (xor within 16-lane group keeps quad)
#pragma unroll
    for (int i = 0; i < 4; i++) {
        float m = mrun[i], l = lrun[i];
#pragma unroll
        for (int off = 1; off <= 8; off <<= 1) {
            float mo = __shfl_xor(m, off);
            float lo = __shfl_xor(l, off);
            float mn = fmaxf(m, mo);
            l = l * __expf(m - mn) + lo * __expf(mo - mn);
            m = mn;
        }
        mrun[i] = m; lrun[i] = l;
    }
    if (l16 == 0) {
#pragma unroll
        for (int i = 0; i < 4; i++) {
            Mred[ks][qs * 16 + quad * 4 + i] = mrun[i];
            Lred[ks][qs * 16 + quad * 4 + i] = lrun[i];
        }
    }
    __syncthreads();
    if (tid < 32) {
        float m0 = Mred[0][tid], m1 = Mred[1][tid];
        float mn = fmaxf(m0, m1);
        float L = Lred[0][tid] * __expf(m0 - mn) + Lred[1][tid] * __expf(m1 - mn);
        Mfin[tid] = mn;
        Lfin[tid] = 1.0f / L;
    }
    __syncthreads();
    float Mi[4], Li[4];
#pragma unroll
    for (int i = 0; i < 4; i++) {
        Mi[i] = Mfin[qs * 16 + quad * 4 + i];
        Li[i] = Lfin[qs * 16 + quad * 4 + i];
    }

    // ---- pass 2: weights + PV ----
    float4v oacc0 = (float4v){0.f, 0.f, 0.f, 0.f};
    float4v oacc1 = (float4v){0.f, 0.f, 0.f, 0.f};
    const int dhalf = ks;
    for (int c = 0; c < nch; c++) {
        int kc = c * 32;
        __syncthreads();
        {
            int r = tid >> 3, c8 = (tid & 7) * 8;
            *(short8*)&Ks[r * 72 + c8] = *(const short8*)&kbase[(size_t)(kc + r) * NQKV + c8];
            int vk = tid & 31, dg = tid >> 5;
            short8 v8 = *(const short8*)&vbase[(size_t)(kc + vk) * NQKV + dg * 8];
#pragma unroll
            for (int i = 0; i < 8; i++) Vt[(dg * 8 + i) * 40 + vk] = v8[i];
        }
        __syncthreads();
        short8 bk0 = *(const short8*)&Ks[(ks * 16 + l16) * 72 + quad * 8];
        short8 bk1 = *(const short8*)&Ks[(ks * 16 + l16) * 72 + 32 + quad * 8];
        float4v acc = (float4v){0.f, 0.f, 0.f, 0.f};
        acc = __builtin_amdgcn_mfma_f32_16x16x32_bf16(aq0, bk0, acc, 0, 0, 0);
        acc = __builtin_amdgcn_mfma_f32_16x16x32_bf16(aq1, bk1, acc, 0, 0, 0);
        int kg = kc + kcol;
#pragma unroll
        for (int i = 0; i < 4; i++) {
            int lrow = qs * 16 + quad * 4 + i;
            int qg = q0 + lrow;
            float p = 0.f;
            if (kg <= qg) p = __expf(acc[i] * 0.125f - Mi[i]) * Li[i];
            wrow[(size_t)lrow * SEQ + kg] = p;
            Ps[lrow * 40 + ks * 16 + l16] = f2bf(p);
        }
        __syncthreads();
        short8 ap  = *(const short8*)&Ps[(qs * 16 + l16) * 40 + quad * 8];
        short8 bv0 = *(const short8*)&Vt[(dhalf * 32 + l16) * 40 + quad * 8];
        short8 bv1 = *(const short8*)&Vt[(dhalf * 32 + 16 + l16) * 40 + quad * 8];
        oacc0 = __builtin_amdgcn_mfma_f32_16x16x32_bf16(ap, bv0, oacc0, 0, 0, 0);
        oacc1 = __builtin_amdgcn_mfma_f32_16x16x32_bf16(ap, bv1, oacc1, 0, 0, 0);
    }

    // zero-fill k in [kend, SEQ) for this tile's 32 rows
    int Z = SEQ - kend;
    if (Z > 0) {
        float4 z4 = make_float4(0.f, 0.f, 0.f, 0.f);
        for (int row = 0; row < 32; row++) {
            float* p = wrow + (size_t)row * SEQ + kend;
            for (int c4 = tid * 4; c4 < Z; c4 += 1024)
                *(float4*)(p + c4) = z4;
        }
    }

    // store attn-head output [B,S,H*D] bf16
    short* obase = aheads + (size_t)(b * SEQ) * EMBED + h * 64;
#pragma unroll
    for (int i = 0; i < 4; i++) {
        int qg = q0 + qs * 16 + quad * 4 + i;
        obase[(size_t)qg * EMBED + dhalf * 32 + l16]      = f2bf(oacc0[i]);
        obase[(size_t)qg * EMBED + dhalf * 32 + 16 + l16] = f2bf(oacc1[i]);
    }
}

// ---------------- launcher ----------------
extern "C" void kernel_launch(void* const* d_in, const int* in_sizes, int n_in,
                              void* d_out, int out_size, void* d_ws, size_t ws_size,
                              hipStream_t stream) {
    const float* hidden = (const float*)d_in[0];
    const float* attn_w = (const float*)d_in[1];
    const float* attn_b = (const float*)d_in[2];
    const float* proj_w = (const float*)d_in[3];
    const float* proj_b = (const float*)d_in[4];

    float* out      = (float*)d_out;
    float* attn_out = out;                                  // [4096,1024] fp32
    float* weights  = out + (size_t)MROWS * EMBED;          // [2,16,2048,2048] fp32

    char* ws = (char*)d_ws;
    short* hid_b   = (short*)(ws);             //  8,388,608 B  [4096][1024] bf16
    short* wqkv_t  = (short*)(ws + 8388608);   //  6,291,456 B  [3072][1024] bf16
    short* wproj_t = (short*)(ws + 14680064);  //  2,097,152 B  [1024][1024] bf16
    short* qkv     = (short*)(ws + 16777216);  // 25,165,824 B  [4096][3072] bf16
    short* aheads  = (short*)(ws + 41943040);  //  8,388,608 B  [4096][1024] bf16

    cast_bf16_k<<<dim3((MROWS * EMBED / 8 + 255) / 256), 256, 0, stream>>>(
        hidden, hid_b, MROWS * EMBED / 8);
    transpose_cast_k<<<dim3(NQKV / 32, EMBED / 32), 256, 0, stream>>>(
        attn_w, wqkv_t, EMBED, NQKV);
    transpose_cast_k<<<dim3(EMBED / 32, EMBED / 32), 256, 0, stream>>>(
        proj_w, wproj_t, EMBED, EMBED);
    gemm_bf16_k<<<dim3(MROWS / 64, NQKV / 64), 256, 0, stream>>>(
        hid_b, wqkv_t, attn_b, nullptr, qkv, MROWS, NQKV, EMBED);
    attn_k<<<dim3(BATCH * HEADS * (SEQ / 32)), 256, 0, stream>>>(
        qkv, weights, aheads);
    gemm_bf16_k<<<dim3(MROWS / 64, EMBED / 64), 256, 0, stream>>>(
        aheads, wproj_t, proj_b, attn_out, nullptr, MROWS, EMBED, EMBED);
}

// Round 2
// 725.086 us; speedup vs baseline: 1.0720x; 1.0720x over previous
//
#include <hip/hip_runtime.h>
#include <hip/hip_bf16.h>

#define EMBED 1024
#define HEADS 16
#define HEAD_DIM 64
#define BATCH 2
#define SEQ 2048
#define MROWS (BATCH*SEQ)   // 4096
#define NQKV  (3*EMBED)     // 3072

typedef __attribute__((ext_vector_type(8))) short short8;
typedef __attribute__((ext_vector_type(4))) float float4v;

static __device__ __forceinline__ short f2bf(float f) {
    union { float f; unsigned u; } x; x.f = f;
    unsigned r = (x.u + 0x7FFFu + ((x.u >> 16) & 1u)) >> 16;
    return (short)r;
}

// async 16B global->LDS (m97 path). LDS dest must be wave-uniform base + lane*16.
static __device__ __forceinline__ void gl_lds16(const short* g, short* l) {
    __builtin_amdgcn_global_load_lds(
        (const __attribute__((address_space(1))) void*)g,
        (__attribute__((address_space(3))) void*)l, 16, 0, 0);
}

// ---------------- cast fp32 -> bf16 ----------------
__global__ __launch_bounds__(256) void cast_bf16_k(const float* __restrict__ in,
                                                   short* __restrict__ out, int n8) {
    int i = blockIdx.x * 256 + threadIdx.x;
    if (i >= n8) return;
    const float4* p = (const float4*)in + (size_t)i * 2;
    float4 a = p[0], b = p[1];
    short8 o;
    o[0] = f2bf(a.x); o[1] = f2bf(a.y); o[2] = f2bf(a.z); o[3] = f2bf(a.w);
    o[4] = f2bf(b.x); o[5] = f2bf(b.y); o[6] = f2bf(b.z); o[7] = f2bf(b.w);
    *((short8*)out + i) = o;
}

// ---------------- transpose + cast: W[K][N] fp32 -> Wt[N][K] bf16 ----------------
__global__ __launch_bounds__(256) void transpose_cast_k(const float* __restrict__ W,
                                                        short* __restrict__ Wt,
                                                        int K, int N) {
    __shared__ float tile[32][33];
    int tx = threadIdx.x & 31, ty = threadIdx.x >> 5;
    int n0 = blockIdx.x * 32, k0 = blockIdx.y * 32;
#pragma unroll
    for (int i = 0; i < 4; i++)
        tile[ty + i * 8][tx] = W[(size_t)(k0 + ty + i * 8) * N + n0 + tx];
    __syncthreads();
#pragma unroll
    for (int i = 0; i < 4; i++)
        Wt[(size_t)(n0 + ty + i * 8) * K + k0 + tx] = f2bf(tile[tx][ty + i * 8]);
}

// ---------------- m97-style 128x128 bf16 GEMM: C = A[M][K] @ Bt[N][K]^T + bias ----------------
// 256 thr = 4 waves in 2x2; each wave 64x64 = 4x4 MFMAs of 16x16x32. BK=32.
__global__ __launch_bounds__(256) void gemm128_k(const short* __restrict__ A,
                                                 const short* __restrict__ Bt,
                                                 const float* __restrict__ bias,
                                                 float* __restrict__ outF,
                                                 short* __restrict__ outB,
                                                 int M, int N, int K) {
    __shared__ __align__(16) short As[128 * 32];   // [row][32k] unpadded (64B rows)
    __shared__ __align__(16) short Bs[128 * 32];
    const int tid = threadIdx.x;
    const int wave = tid >> 6, lane = tid & 63, quad = lane >> 4, l16 = lane & 15;
    const int wm = wave >> 1, wn = wave & 1;
    const int m0 = blockIdx.x * 128, n0 = blockIdx.y * 128;

    float4v acc[4][4];
#pragma unroll
    for (int mi = 0; mi < 4; mi++)
#pragma unroll
        for (int ni = 0; ni < 4; ni++) acc[mi][ni] = (float4v){0.f, 0.f, 0.f, 0.f};

    // staging coords: flat 16B-chunk f = wave*128 + j*64 + lane ; row=f>>2 c=f&3
    const int rA0 = wave * 32 + (lane >> 2), cA = (lane & 3) * 8;
    const size_t arow0 = (size_t)(m0 + rA0) * K, arow1 = (size_t)(m0 + rA0 + 16) * K;
    const size_t brow0 = (size_t)(n0 + rA0) * K, brow1 = (size_t)(n0 + rA0 + 16) * K;
    short* ldsA0 = &As[(wave * 128 + lane) * 8];
    short* ldsA1 = &As[(wave * 128 + 64 + lane) * 8];
    short* ldsB0 = &Bs[(wave * 128 + lane) * 8];
    short* ldsB1 = &Bs[(wave * 128 + 64 + lane) * 8];

    for (int k0 = 0; k0 < K; k0 += 32) {
        __syncthreads();
        gl_lds16(A + arow0 + k0 + cA, ldsA0);
        gl_lds16(A + arow1 + k0 + cA, ldsA1);
        gl_lds16(Bt + brow0 + k0 + cA, ldsB0);
        gl_lds16(Bt + brow1 + k0 + cA, ldsB1);
        __syncthreads();
        short8 a[4], b[4];
#pragma unroll
        for (int mi = 0; mi < 4; mi++)
            a[mi] = *(const short8*)&As[(wm * 64 + mi * 16 + l16) * 32 + quad * 8];
#pragma unroll
        for (int ni = 0; ni < 4; ni++)
            b[ni] = *(const short8*)&Bs[(wn * 64 + ni * 16 + l16) * 32 + quad * 8];
#pragma unroll
        for (int mi = 0; mi < 4; mi++)
#pragma unroll
            for (int ni = 0; ni < 4; ni++)
                acc[mi][ni] = __builtin_amdgcn_mfma_f32_16x16x32_bf16(a[mi], b[ni], acc[mi][ni], 0, 0, 0);
    }

#pragma unroll
    for (int ni = 0; ni < 4; ni++) {
        int col = n0 + wn * 64 + ni * 16 + l16;
        float bv = bias ? bias[col] : 0.f;
#pragma unroll
        for (int mi = 0; mi < 4; mi++) {
            int row = m0 + wm * 64 + mi * 16 + quad * 4;
            if (outF) {
#pragma unroll
                for (int i = 0; i < 4; i++)
                    outF[(size_t)(row + i) * N + col] = acc[mi][ni][i] + bv;
            } else {
#pragma unroll
                for (int i = 0; i < 4; i++)
                    outB[(size_t)(row + i) * N + col] = f2bf(acc[mi][ni][i] + bv);
            }
        }
    }
}

// ---------------- fused causal attention ----------------
// Block = 256 thr (4 waves); one (b,h), 64 query rows (wave w owns rows w*16..w*16+15).
// k-chunks of 64. Pass 1: softmax stats (MFMA QK^T, online m/l, 16-lane butterfly).
// Pass 2: recompute scores, write normalized weights, PV MFMA. Then zero-fill.
__global__ __launch_bounds__(256) void attn_k(const short* __restrict__ qkv,
                                              float* __restrict__ wout,
                                              short* __restrict__ aheads) {
    __shared__ __align__(16) short Qs[2][64 * 32];  // [dhalf][row][32d] 64B rows
    __shared__ __align__(16) short Ks[2][64 * 32];
    __shared__ __align__(16) short Vt[64 * 72];     // [d][k] padded (144B rows)
    __shared__ __align__(16) short Ps[64 * 72];     // [q][k] bf16 p

    const int tid = threadIdx.x;
    const int wave = tid >> 6, lane = tid & 63, quad = lane >> 4, l16 = lane & 15;
    const int bh = blockIdx.x & 31;
    const int b = bh >> 4, h = bh & 15;
    const int qt = 31 - (blockIdx.x >> 5);       // heavy tiles dispatched first
    const int q0 = qt * 64;
    const int nch = qt + 1;                      // 64-wide k-chunks

    const short* qbase = qkv + (size_t)(b * SEQ) * NQKV + h * 64;
    const short* kbase = qbase + EMBED;
    const short* vbase = qbase + 2 * EMBED;
    float* wrow = wout + ((size_t)bh * SEQ + q0) * SEQ;

    // ---- stage Q (once): two m97-layout halves ----
    {
        const int r = lane >> 2, c = (lane & 3) * 8;
        gl_lds16(qbase + (size_t)(q0 + wave * 16 + r) * NQKV + c,
                 &Qs[0][(wave * 64 + lane) * 8]);
        gl_lds16(qbase + (size_t)(q0 + wave * 16 + r) * NQKV + 32 + c,
                 &Qs[1][(wave * 64 + lane) * 8]);
    }
    __syncthreads();
    short8 aq0 = *(const short8*)&Qs[0][(wave * 16 + l16) * 32 + quad * 8];
    short8 aq1 = *(const short8*)&Qs[1][(wave * 16 + l16) * 32 + quad * 8];

    const int kr = lane >> 2, kc16 = (lane & 3) * 8;   // K staging coords
    const int vkp = (tid & 31) * 2, vd8 = (tid >> 5) * 8;  // V staging coords

    float m[4], l[4];
#pragma unroll
    for (int i = 0; i < 4; i++) { m[i] = -1e30f; l[i] = 0.f; }

    // ---- pass 1: stats ----
    for (int c = 0; c < nch; c++) {
        const int kc = c * 64;
        __syncthreads();
        gl_lds16(kbase + (size_t)(kc + wave * 16 + kr) * NQKV + kc16,
                 &Ks[0][(wave * 64 + lane) * 8]);
        gl_lds16(kbase + (size_t)(kc + wave * 16 + kr) * NQKV + 32 + kc16,
                 &Ks[1][(wave * 64 + lane) * 8]);
        __syncthreads();
        float4v sc[4];
#pragma unroll
        for (int kg = 0; kg < 4; kg++) {
            short8 bk0 = *(const short8*)&Ks[0][(kg * 16 + l16) * 32 + quad * 8];
            short8 bk1 = *(const short8*)&Ks[1][(kg * 16 + l16) * 32 + quad * 8];
            float4v s = (float4v){0.f, 0.f, 0.f, 0.f};
            s = __builtin_amdgcn_mfma_f32_16x16x32_bf16(aq0, bk0, s, 0, 0, 0);
            s = __builtin_amdgcn_mfma_f32_16x16x32_bf16(aq1, bk1, s, 0, 0, 0);
            sc[kg] = s;
        }
        if (c < qt) {  // fully valid chunk
#pragma unroll
            for (int i = 0; i < 4; i++) {
                float mx = m[i];
#pragma unroll
                for (int kg = 0; kg < 4; kg++) mx = fmaxf(mx, sc[kg][i] * 0.125f);
                float s0 = 0.f;
#pragma unroll
                for (int kg = 0; kg < 4; kg++) s0 += __expf(sc[kg][i] * 0.125f - mx);
                l[i] = l[i] * __expf(m[i] - mx) + s0;
                m[i] = mx;
            }
        } else {       // diagonal chunk: mask kcol > qrow
#pragma unroll
            for (int i = 0; i < 4; i++) {
                int qrl = wave * 16 + quad * 4 + i;
                float mx = m[i];
#pragma unroll
                for (int kg = 0; kg < 4; kg++)
                    if (kg * 16 + l16 <= qrl) mx = fmaxf(mx, sc[kg][i] * 0.125f);
                float s0 = 0.f;
#pragma unroll
                for (int kg = 0; kg < 4; kg++)
                    if (kg * 16 + l16 <= qrl) s0 += __expf(sc[kg][i] * 0.125f - mx);
                l[i] = l[i] * __expf(m[i] - mx) + s0;
                m[i] = mx;
            }
        }
    }
    // 16-lane butterfly (cols of each row live in l16 lanes of the same quad-row)
    float Mi[4], Li[4];
#pragma unroll
    for (int i = 0; i < 4; i++) {
        float mm = m[i], ll = l[i];
#pragma unroll
        for (int off = 1; off <= 8; off <<= 1) {
            float mo = __shfl_xor(mm, off);
            float lo = __shfl_xor(ll, off);
            float mn = fmaxf(mm, mo);
            ll = ll * __expf(mm - mn) + lo * __expf(mo - mn);
            mm = mn;
        }
        Mi[i] = mm; Li[i] = 1.0f / ll;
    }

    // ---- pass 2: weights + PV ----
    float4v oacc[4];
#pragma unroll
    for (int dg = 0; dg < 4; dg++) oacc[dg] = (float4v){0.f, 0.f, 0.f, 0.f};

    for (int c = 0; c < nch; c++) {
        const int kc = c * 64;
        __syncthreads();
        gl_lds16(kbase + (size_t)(kc + wave * 16 + kr) * NQKV + kc16,
                 &Ks[0][(wave * 64 + lane) * 8]);
        gl_lds16(kbase + (size_t)(kc + wave * 16 + kr) * NQKV + 32 + kc16,
                 &Ks[1][(wave * 64 + lane) * 8]);
        {   // V transpose staging: thread covers k rows (vkp,vkp+1), d cols vd8..vd8+7
            short8 va = *(const short8*)&vbase[(size_t)(kc + vkp) * NQKV + vd8];
            short8 vb = *(const short8*)&vbase[(size_t)(kc + vkp + 1) * NQKV + vd8];
#pragma unroll
            for (int i = 0; i < 8; i++) {
                short2 pk; pk.x = va[i]; pk.y = vb[i];
                *(short2*)&Vt[(vd8 + i) * 72 + vkp] = pk;
            }
        }
        __syncthreads();
        float4v sc[4];
#pragma unroll
        for (int kg = 0; kg < 4; kg++) {
            short8 bk0 = *(const short8*)&Ks[0][(kg * 16 + l16) * 32 + quad * 8];
            short8 bk1 = *(const short8*)&Ks[1][(kg * 16 + l16) * 32 + quad * 8];
            float4v s = (float4v){0.f, 0.f, 0.f, 0.f};
            s = __builtin_amdgcn_mfma_f32_16x16x32_bf16(aq0, bk0, s, 0, 0, 0);
            s = __builtin_amdgcn_mfma_f32_16x16x32_bf16(aq1, bk1, s, 0, 0, 0);
            sc[kg] = s;
        }
        const bool diag = (c == qt);
#pragma unroll
        for (int i = 0; i < 4; i++) {
            int lrow = wave * 16 + quad * 4 + i;
            float* wr = wrow + (size_t)lrow * SEQ + kc;
#pragma unroll
            for (int kg = 0; kg < 4; kg++) {
                float p = 0.f;
                if (!diag || (kg * 16 + l16 <= lrow))
                    p = __expf(sc[kg][i] * 0.125f - Mi[i]) * Li[i];
                wr[kg * 16 + l16] = p;
                Ps[lrow * 72 + kg * 16 + l16] = f2bf(p);
            }
        }
        // PV: wave's own 16 rows (Ps region written+read by same wave; no barrier)
#pragma unroll
        for (int kh = 0; kh < 2; kh++) {
            short8 ap = *(const short8*)&Ps[(wave * 16 + l16) * 72 + kh * 32 + quad * 8];
#pragma unroll
            for (int dg = 0; dg < 4; dg++) {
                short8 bv = *(const short8*)&Vt[(dg * 16 + l16) * 72 + kh * 32 + quad * 8];
                oacc[dg] = __builtin_amdgcn_mfma_f32_16x16x32_bf16(ap, bv, oacc[dg], 0, 0, 0);
            }
        }
    }

    // ---- zero-fill upper region [kend, SEQ) ----
    const int kend = (qt + 1) * 64;
    if (kend < SEQ) {
        float4 z4 = make_float4(0.f, 0.f, 0.f, 0.f);
        for (int row = 0; row < 64; row++) {
            float* p = wrow + (size_t)row * SEQ;
            for (int cc = kend + tid * 4; cc < SEQ; cc += 1024)
                *(float4*)(p + cc) = z4;
        }
    }

    // ---- store attn-head output [B,S,H*D] bf16 ----
    short* obase = aheads + (size_t)(b * SEQ) * EMBED + h * 64;
#pragma unroll
    for (int i = 0; i < 4; i++) {
        int qg = q0 + wave * 16 + quad * 4 + i;
#pragma unroll
        for (int dg = 0; dg < 4; dg++)
            obase[(size_t)qg * EMBED + dg * 16 + l16] = f2bf(oacc[dg][i]);
    }
}

// ---------------- launcher ----------------
extern "C" void kernel_launch(void* const* d_in, const int* in_sizes, int n_in,
                              void* d_out, int out_size, void* d_ws, size_t ws_size,
                              hipStream_t stream) {
    const float* hidden = (const float*)d_in[0];
    const float* attn_w = (const float*)d_in[1];
    const float* attn_b = (const float*)d_in[2];
    const float* proj_w = (const float*)d_in[3];
    const float* proj_b = (const float*)d_in[4];

    float* out      = (float*)d_out;
    float* attn_out = out;                                  // [4096,1024] fp32
    float* weights  = out + (size_t)MROWS * EMBED;          // [2,16,2048,2048] fp32

    char* ws = (char*)d_ws;
    short* hid_b   = (short*)(ws);             //  8 MB  [4096][1024] bf16
    short* wqkv_t  = (short*)(ws + 8388608);   //  6 MB  [3072][1024] bf16
    short* wproj_t = (short*)(ws + 14680064);  //  2 MB  [1024][1024] bf16
    short* qkv     = (short*)(ws + 16777216);  // 24 MB  [4096][3072] bf16
    short* aheads  = (short*)(ws + 41943040);  //  8 MB  [4096][1024] bf16

    cast_bf16_k<<<dim3((MROWS * EMBED / 8 + 255) / 256), 256, 0, stream>>>(
        hidden, hid_b, MROWS * EMBED / 8);
    transpose_cast_k<<<dim3(NQKV / 32, EMBED / 32), 256, 0, stream>>>(
        attn_w, wqkv_t, EMBED, NQKV);
    transpose_cast_k<<<dim3(EMBED / 32, EMBED / 32), 256, 0, stream>>>(
        proj_w, wproj_t, EMBED, EMBED);
    gemm128_k<<<dim3(MROWS / 128, NQKV / 128), 256, 0, stream>>>(
        hid_b, wqkv_t, attn_b, nullptr, qkv, MROWS, NQKV, EMBED);
    attn_k<<<dim3(BATCH * HEADS * (SEQ / 64)), 256, 0, stream>>>(
        qkv, weights, aheads);
    gemm128_k<<<dim3(MROWS / 128, EMBED / 128), 256, 0, stream>>>(
        aheads, wproj_t, proj_b, attn_out, nullptr, MROWS, EMBED, EMBED);
}